// Round 9
// baseline (124.937 us; speedup 1.0000x reference)
//
#include <hip/hip_runtime.h>
#include <hip/hip_bf16.h>
#include <math.h>

// Problem constants (fixed by setup_inputs)
#define NN   5570
#define BB   16
#define CIN  35
#define MPAD 5632      // NN padded to 88*64
#define NCHUNK 176     // MPAD/32  (k-chunks of 32)
#define OUTER 11       // split-K slices (blockIdx.y); 16 chunks = 512 k each
#define CPS  16        // chunks per slice

// workspace layout (float offsets); total 5,060,608 floats ~= 20.2 MB
#define OFF_RSUM 0                          // [OUTER][MPAD] fp32 = 61952
#define OFF_G0C  61952                      // [BB][NN][4] fp32 = 356480
#define OFF_PGP  418432                     // [OUTER][BB][NN][4] fp32 = 3921280
#define OFF_GTF  4339712                    // gtf bf16 [NCHUNK][BB][64][8]

typedef __attribute__((ext_vector_type(8))) short  short8;
typedef __attribute__((ext_vector_type(4))) float  floatx4;

static __device__ inline ushort f2bf(float f) {
    union { __hip_bfloat16 h; ushort u; } cv;
    cv.h = __float2bfloat16(f);
    return cv.u;
}

// ---------------------------------------------------------------------------
// Kernel G: per (b, m):
//   a0[dj] = sum_c x[b,m,c]*w_k0[d,c,j];  g0c[b][m][j] = sum_d E[m,d]*a0[dj]
//   a1[dj] = sum_c x[b,m,c]*w_k1[d,c,j] -> gtf bf16 in MFMA-B-fragment order:
//       gtf[((ck*16 + b)*64 + quad*16 + dj)*8 + u],  m = ck*32 + quad*8 + u
// Writes go through an LDS transpose so global stores are coalesced short8.
// ---------------------------------------------------------------------------
__global__ __launch_bounds__(256)
void kg_g(const float* __restrict__ x, const float* __restrict__ e,
          const float* __restrict__ wg, const float* __restrict__ wu,
          float* __restrict__ g0c, ushort* __restrict__ gtf) {
    __shared__ float xs[256 * CIN];
    __shared__ float wl[8 * CIN * 4];    // [(k*4+d)*35 + c]*4 + j
    __shared__ ushort ls[256 * 17];      // staged a1, row stride 17 (pad)
    int tid = threadIdx.x;
    int b   = blockIdx.y;
    int m0  = blockIdx.x * 256;

    for (int i = tid; i < 8 * CIN * 4; i += 256) {
        int j = i & 3, rest = i >> 2;
        int c = rest % CIN, kd = rest / CIN;
        int k = kd >> 2, d = kd & 3;
        float v;
        if (j < 2) v = wg[((d * 2 + k) * 37 + c) * 4 + 2 + j];
        else       v = wu[((d * 2 + k) * 37 + c) * 2 + (j - 2)];
        wl[i] = v;
    }
    int rows = NN - m0; if (rows > 256) rows = 256; if (rows < 0) rows = 0;
    const float* xsrc = x + ((size_t)b * NN + m0) * CIN;
    for (int i = tid; i < rows * CIN; i += 256) xs[i] = xsrc[i];
    __syncthreads();

    int m = m0 + tid;
    float a1[16];
    #pragma unroll
    for (int i = 0; i < 16; ++i) a1[i] = 0.f;

    if (m < NN) {
        float a0[16];
        #pragma unroll
        for (int i = 0; i < 16; ++i) a0[i] = 0.f;
        for (int c = 0; c < CIN; ++c) {
            float xa = xs[tid * CIN + c];
            #pragma unroll
            for (int kd = 0; kd < 8; ++kd) {
                const float4 w = *(const float4*)&wl[(kd * CIN + c) * 4];
                const int d4 = (kd & 3) * 4;
                if (kd < 4) {
                    a0[d4+0] += xa*w.x; a0[d4+1] += xa*w.y;
                    a0[d4+2] += xa*w.z; a0[d4+3] += xa*w.w;
                } else {
                    a1[d4+0] += xa*w.x; a1[d4+1] += xa*w.y;
                    a1[d4+2] += xa*w.z; a1[d4+3] += xa*w.w;
                }
            }
        }
        // fold E-contraction for k=0 term: p0[j] = sum_d E[m,d]*a0[d*4+j]
        float4 em4 = ((const float4*)e)[m];
        float p0[4];
        #pragma unroll
        for (int j = 0; j < 4; ++j)
            p0[j] = em4.x*a0[j] + em4.y*a0[4+j] + em4.z*a0[8+j] + em4.w*a0[12+j];
        ((float4*)g0c)[(size_t)b * NN + m] = make_float4(p0[0], p0[1], p0[2], p0[3]);
    }

    // stage a1 -> LDS [m_local][dj] (stride 17)
    #pragma unroll
    for (int dj = 0; dj < 16; ++dj) ls[tid * 17 + dj] = f2bf(a1[dj]);
    __syncthreads();

    // coalesced write-out: wave w handles local chunks {2w, 2w+1}
    const int wave = tid >> 6, lane = tid & 63;
    const int qo = lane >> 4, dj = lane & 15;
    #pragma unroll
    for (int i = 0; i < 2; ++i) {
        const int lc = wave * 2 + i;
        const int ck = blockIdx.x * 8 + lc;
        short8 v;
        #pragma unroll
        for (int u = 0; u < 8; ++u)
            v[u] = (short)ls[(lc * 32 + qo * 8 + u) * 17 + dj];
        *(short8*)&gtf[((size_t)(ck * 16 + b)) * 512 + lane * 8] = v;
    }
}

// ---------------------------------------------------------------------------
// Kernel B (fused score-gen + MFMA, LDS double-buffered B, 2 row-tiles/wave):
//   PG contribution over slice s: sum_m exp(relu(E_n.E_m)) * G1[m][col]
//   rsums[s][n] = per-slice row sum of scores (no atomics)
// Block = 4 waves; wave w owns row-tiles rt0 = bx*8+w, rt1 = rt0+4, all 16
// col-tiles. Per step (32 k): DMA next 16KB B-chunk into LDS (overlaps this
// step's compute), 16 scores/lane (2 A-frags), 16 ds_read_b128 B-frags each
// feeding 2 MFMAs (B amortized over both row-tiles -> half LDS/VMEM traffic).
// ---------------------------------------------------------------------------
static __device__ inline void load_chunk(const ushort* __restrict__ gsrc,
                                         ushort* ldst, int tid, int wave) {
    #pragma unroll
    for (int i = 0; i < 4; ++i) {
        const ushort* g = gsrc + (size_t)(i * 256 + tid) * 8;
        ushort* l = ldst + (size_t)(i * 256 + wave * 64) * 8;  // wave-uniform base
        __builtin_amdgcn_global_load_lds(
            (const __attribute__((address_space(1))) unsigned int*)g,
            (__attribute__((address_space(3))) unsigned int*)l, 16, 0, 0);
    }
}

template <bool CHECK>
__device__ __forceinline__ void kb_main(const float4* __restrict__ esl,
                                        const ushort* __restrict__ gsl,
                                        ushort (*sbuf)[8192],
                                        const float4 en0, const float4 en1,
                                        int k0m, int tid, int wave, int lane,
                                        int quad, floatx4 (&acc)[2][16],
                                        float& rs0, float& rs1) {
    #pragma unroll 2
    for (int st = 0; st < CPS; ++st) {
        __syncthreads();   // chunk st resident; prior reads of buf[(st+1)&1] done
        if (st + 1 < CPS)
            load_chunk(gsl + (size_t)(st + 1) * 8192, sbuf[(st + 1) & 1], tid, wave);

        // scores: lane holds A[rt*16+l15][quad*8+u] for both row-tiles
        short8 af0, af1;
        const int stq = st * 32 + quad * 8;
        #pragma unroll
        for (int u = 0; u < 8; ++u) {
            float4 em = esl[stq + u];
            float d0 = en0.x*em.x + en0.y*em.y + en0.z*em.z + en0.w*em.w;
            float d1 = en1.x*em.x + en1.y*em.y + en1.z*em.z + en1.w*em.w;
            float s0 = __expf(fmaxf(d0, 0.f));
            float s1 = __expf(fmaxf(d1, 0.f));
            if (CHECK && (k0m + stq + u >= NN)) { s0 = 0.f; s1 = 0.f; }
            rs0 += s0; rs1 += s1;
            af0[u] = (short)f2bf(s0);
            af1[u] = (short)f2bf(s1);
        }

        const ushort* bb = &sbuf[st & 1][lane * 8];
        #pragma unroll
        for (int ct = 0; ct < 16; ++ct) {
            short8 bf = *(const short8*)&bb[ct * 512];
            acc[0][ct] = __builtin_amdgcn_mfma_f32_16x16x32_bf16(af0, bf, acc[0][ct], 0, 0, 0);
            acc[1][ct] = __builtin_amdgcn_mfma_f32_16x16x32_bf16(af1, bf, acc[1][ct], 0, 0, 0);
        }
    }
}

__global__ __launch_bounds__(256, 2)
void kb_pg(const float* __restrict__ e, const ushort* __restrict__ gtf,
           float* __restrict__ pgp, float* __restrict__ rsums) {
    __shared__ ushort sbuf[2][8192];     // double-buffered B chunk, 32 KB
    __shared__ float4 esl[512];          // slice's E rows, 8 KB
    const int tid  = threadIdx.x;
    const int wave = tid >> 6;
    const int lane = tid & 63;
    const int l15  = lane & 15;
    const int quad = lane >> 4;
    const int rt0  = blockIdx.x * 8 + wave;
    const int rt1  = rt0 + 4;
    const int s    = blockIdx.y;
    const int k0m  = s * (CPS * 32);     // first m of slice
    const float4* E4 = (const float4*)e;

    // stage slice E rows + first B chunk
    for (int i = tid; i < 512; i += 256) {
        int m = k0m + i;
        esl[i] = (m < NN) ? E4[m] : make_float4(0.f, 0.f, 0.f, 0.f);
    }
    const ushort* gsl = gtf + (size_t)s * CPS * 8192;
    load_chunk(gsl, sbuf[0], tid, wave);

    const int nr0 = rt0 * 16 + l15;
    const int nr1 = rt1 * 16 + l15;
    const float4 en0 = E4[nr0 < NN ? nr0 : 0];
    const float4 en1 = E4[nr1 < NN ? nr1 : 0];

    floatx4 acc[2][16];
    #pragma unroll
    for (int r = 0; r < 2; ++r)
        #pragma unroll
        for (int i = 0; i < 16; ++i) acc[r][i] = (floatx4){0.f, 0.f, 0.f, 0.f};
    float rs0 = 0.f, rs1 = 0.f;

    if (k0m + CPS * 32 <= NN)
        kb_main<false>(esl, gsl, sbuf, en0, en1, k0m, tid, wave, lane, quad, acc, rs0, rs1);
    else
        kb_main<true >(esl, gsl, sbuf, en0, en1, k0m, tid, wave, lane, quad, acc, rs0, rs1);

    // rsums: row l15, partial per quad -> butterfly over quads, quad0 stores
    rs0 += __shfl_xor(rs0, 16); rs0 += __shfl_xor(rs0, 32);
    rs1 += __shfl_xor(rs1, 16); rs1 += __shfl_xor(rs1, 32);
    if (quad == 0) {
        rsums[(size_t)s * MPAD + nr0] = rs0;   // nr < MPAD always
        rsums[(size_t)s * MPAD + nr1] = rs1;
    }

    // epilogue: acc[r][ct][j] = D[n = rt_r*16+quad*4+j][dj = l15]
    // contract dj = d*4+jj with E[n,d]: reduce over d via shfl_xor(4),(8)
    const int dsel = l15 >> 2, jj = l15 & 3;
    #pragma unroll
    for (int r = 0; r < 2; ++r) {
        const int rtb = (r == 0 ? rt0 : rt1) * 16 + quad * 4;
        float end[4];
        #pragma unroll
        for (int j = 0; j < 4; ++j) {
            int n = rtb + j;
            end[j] = (n < NN) ? e[n * 4 + dsel] : 0.f;
        }
        #pragma unroll
        for (int ct = 0; ct < 16; ++ct) {
            #pragma unroll
            for (int j = 0; j < 4; ++j) {
                float v = end[j] * acc[r][ct][j];
                v += __shfl_xor(v, 4);
                v += __shfl_xor(v, 8);
                int n = rtb + j;
                if (l15 < 4 && n < NN)
                    pgp[(((size_t)s * BB + ct) * NN + n) * 4 + jj] = v;
            }
        }
    }
}

// ---------------------------------------------------------------------------
// Kernel E: tiny epilogue
// pre[j] = g0c[b][n][j] + (1/sum_s rsums[s][n]) * sum_s pgp[s][b][n][j]
//          + sum_d E[n,d]*bias[d][j]
// R=sigmoid(pre[0..1]), C=tanh(pre[2..3]), h=(1-R)*C, y = relu(h)@lin_w + lin_b
// ---------------------------------------------------------------------------
static __device__ inline float fsig(float x) {
    return 1.f / (1.f + __expf(-x));
}
static __device__ inline float ftanh(float x) {
    float t = __expf(fminf(2.f * x, 80.f));
    return (t - 1.f) / (t + 1.f);
}

__global__ __launch_bounds__(256)
void ke_out(const float* __restrict__ e, const float* __restrict__ rsums,
            const float* __restrict__ g0c, const float* __restrict__ pgp,
            const float* __restrict__ bg, const float* __restrict__ bu,
            const float* __restrict__ lw, const float* __restrict__ lb,
            float* __restrict__ out) {
    int n = blockIdx.x * 256 + threadIdx.x;
    int b = blockIdx.y;
    if (n >= NN) return;
    float4 ev = ((const float4*)e)[n];
    float ed[4] = {ev.x, ev.y, ev.z, ev.w};
    float den = 0.f;
    #pragma unroll
    for (int s = 0; s < OUTER; ++s) den += rsums[(size_t)s * MPAD + n];
    float rd = 1.f / den;

    float pgf[4] = {0.f, 0.f, 0.f, 0.f};
    #pragma unroll
    for (int s = 0; s < OUTER; ++s) {
        float4 t = ((const float4*)pgp)[((size_t)s * BB + b) * NN + n];
        pgf[0] += t.x; pgf[1] += t.y; pgf[2] += t.z; pgf[3] += t.w;
    }
    float4 g0v = ((const float4*)g0c)[(size_t)b * NN + n];
    float g0f[4] = {g0v.x, g0v.y, g0v.z, g0v.w};

    float pre[4];
    #pragma unroll
    for (int j = 0; j < 4; ++j) {
        float bj = 0.f;
        #pragma unroll
        for (int d = 0; d < 4; ++d) {
            float bp = (j < 2) ? bg[d * 4 + 2 + j] : bu[d * 2 + (j - 2)];
            bj += ed[d] * bp;
        }
        pre[j] = g0f[j] + rd * pgf[j] + bj;
    }
    float R0 = fsig(pre[0]);
    float R1 = fsig(pre[1]);
    float C0 = ftanh(pre[2]);
    float C1 = ftanh(pre[3]);
    float h0 = (1.f - R0) * C0;
    float h1 = (1.f - R1) * C1;
    float y = fmaxf(h0, 0.f) * lw[0] + fmaxf(h1, 0.f) * lw[1] + lb[0];
    out[(size_t)b * NN + n] = y;
}

// ---------------------------------------------------------------------------
extern "C" void kernel_launch(void* const* d_in, const int* in_sizes, int n_in,
                              void* d_out, int out_size, void* d_ws, size_t ws_size,
                              hipStream_t stream) {
    const float* x  = (const float*)d_in[0];
    const float* e  = (const float*)d_in[1];
    const float* wg = (const float*)d_in[2];
    const float* bg = (const float*)d_in[3];
    const float* wu = (const float*)d_in[4];
    const float* bu = (const float*)d_in[5];
    const float* lw = (const float*)d_in[6];
    const float* lb = (const float*)d_in[7];
    float* out = (float*)d_out;

    float*  wsf   = (float*)d_ws;
    float*  rsums = wsf + OFF_RSUM;
    float*  g0c   = wsf + OFF_G0C;
    float*  pgp   = wsf + OFF_PGP;
    ushort* gtf   = (ushort*)(wsf + OFF_GTF);

    hipLaunchKernelGGL(kg_g, dim3(22, 16), dim3(256), 0, stream, x, e, wg, wu, g0c, gtf);
    hipLaunchKernelGGL(kb_pg, dim3(44, OUTER), dim3(256), 0, stream, e, gtf, pgp, rsums);
    hipLaunchKernelGGL(ke_out, dim3(22, 16), dim3(256), 0, stream,
                       e, rsums, g0c, pgp, bg, bu, lw, lb, out);
}

// Round 10
// 121.749 us; speedup vs baseline: 1.0262x; 1.0262x over previous
//
#include <hip/hip_runtime.h>
#include <hip/hip_bf16.h>
#include <math.h>

// Problem constants (fixed by setup_inputs)
#define NN   5570
#define BB   16
#define CIN  35
#define MPAD 5632      // NN padded to 88*64
#define NCHUNK 176     // MPAD/32  (k-chunks of 32)
#define OUTER 11       // split-K slices (blockIdx.y); 16 chunks = 512 k each
#define CPS  16        // chunks per slice

// workspace layout (float offsets); total 5,060,608 floats ~= 20.2 MB
#define OFF_RSUM 0                          // [OUTER][MPAD] fp32 = 61952
#define OFF_G0C  61952                      // [BB][NN][4] fp32 = 356480
#define OFF_PGP  418432                     // [OUTER][BB][NN][4] fp32 = 3921280
#define OFF_GTF  4339712                    // gtf bf16 [NCHUNK][BB][64][8]

typedef __attribute__((ext_vector_type(8))) short  short8;
typedef __attribute__((ext_vector_type(4))) float  floatx4;

static __device__ inline ushort f2bf(float f) {
    union { __hip_bfloat16 h; ushort u; } cv;
    cv.h = __float2bfloat16(f);
    return cv.u;
}

// ---------------------------------------------------------------------------
// Kernel G: per (b, m):
//   a0[dj] = sum_c x[b,m,c]*w_k0[d,c,j];  g0c[b][m][j] = sum_d E[m,d]*a0[dj]
//   a1[dj] = sum_c x[b,m,c]*w_k1[d,c,j] -> gtf bf16 in MFMA-B-fragment order:
//       gtf[((ck*16 + b)*64 + quad*16 + dj)*8 + u],  m = ck*32 + quad*8 + u
// Writes go through an LDS transpose so global stores are coalesced short8.
// ---------------------------------------------------------------------------
__global__ __launch_bounds__(256)
void kg_g(const float* __restrict__ x, const float* __restrict__ e,
          const float* __restrict__ wg, const float* __restrict__ wu,
          float* __restrict__ g0c, ushort* __restrict__ gtf) {
    __shared__ float xs[256 * CIN];
    __shared__ float wl[8 * CIN * 4];    // [(k*4+d)*35 + c]*4 + j
    __shared__ ushort ls[256 * 17];      // staged a1, row stride 17 (pad)
    int tid = threadIdx.x;
    int b   = blockIdx.y;
    int m0  = blockIdx.x * 256;

    for (int i = tid; i < 8 * CIN * 4; i += 256) {
        int j = i & 3, rest = i >> 2;
        int c = rest % CIN, kd = rest / CIN;
        int k = kd >> 2, d = kd & 3;
        float v;
        if (j < 2) v = wg[((d * 2 + k) * 37 + c) * 4 + 2 + j];
        else       v = wu[((d * 2 + k) * 37 + c) * 2 + (j - 2)];
        wl[i] = v;
    }
    int rows = NN - m0; if (rows > 256) rows = 256; if (rows < 0) rows = 0;
    const float* xsrc = x + ((size_t)b * NN + m0) * CIN;
    for (int i = tid; i < rows * CIN; i += 256) xs[i] = xsrc[i];
    __syncthreads();

    int m = m0 + tid;
    float a1[16];
    #pragma unroll
    for (int i = 0; i < 16; ++i) a1[i] = 0.f;

    if (m < NN) {
        float a0[16];
        #pragma unroll
        for (int i = 0; i < 16; ++i) a0[i] = 0.f;
        for (int c = 0; c < CIN; ++c) {
            float xa = xs[tid * CIN + c];
            #pragma unroll
            for (int kd = 0; kd < 8; ++kd) {
                const float4 w = *(const float4*)&wl[(kd * CIN + c) * 4];
                const int d4 = (kd & 3) * 4;
                if (kd < 4) {
                    a0[d4+0] += xa*w.x; a0[d4+1] += xa*w.y;
                    a0[d4+2] += xa*w.z; a0[d4+3] += xa*w.w;
                } else {
                    a1[d4+0] += xa*w.x; a1[d4+1] += xa*w.y;
                    a1[d4+2] += xa*w.z; a1[d4+3] += xa*w.w;
                }
            }
        }
        // fold E-contraction for k=0 term: p0[j] = sum_d E[m,d]*a0[d*4+j]
        float4 em4 = ((const float4*)e)[m];
        float p0[4];
        #pragma unroll
        for (int j = 0; j < 4; ++j)
            p0[j] = em4.x*a0[j] + em4.y*a0[4+j] + em4.z*a0[8+j] + em4.w*a0[12+j];
        ((float4*)g0c)[(size_t)b * NN + m] = make_float4(p0[0], p0[1], p0[2], p0[3]);
    }

    // stage a1 -> LDS [m_local][dj] (stride 17)
    #pragma unroll
    for (int dj = 0; dj < 16; ++dj) ls[tid * 17 + dj] = f2bf(a1[dj]);
    __syncthreads();

    // coalesced write-out: wave w handles local chunks {2w, 2w+1}
    const int wave = tid >> 6, lane = tid & 63;
    const int qo = lane >> 4, dj = lane & 15;
    #pragma unroll
    for (int i = 0; i < 2; ++i) {
        const int lc = wave * 2 + i;
        const int ck = blockIdx.x * 8 + lc;
        short8 v;
        #pragma unroll
        for (int u = 0; u < 8; ++u)
            v[u] = (short)ls[(lc * 32 + qo * 8 + u) * 17 + dj];
        *(short8*)&gtf[((size_t)(ck * 16 + b)) * 512 + lane * 8] = v;
    }
}

// ---------------------------------------------------------------------------
// Kernel B (fused score-gen + MFMA, LDS double-buffered B via global_load_lds):
//   PG contribution over slice s: sum_m exp(relu(E_n.E_m)) * G1[m][col]
//   rsums[s][n] = per-slice row sum of scores (no atomics)
// Block = 4 waves; wave w owns row-tile rt = bx*4+w, all 16 col-tiles.
// Per step (32 k): prefetch next 16KB B-chunk into LDS (async DMA, issued
// right after the barrier so it overlaps this step's compute), compute 8
// scores/lane into the A-frag, 16 ds_read_b128 B-frags, 16 MFMA.
// 40 KB LDS -> 4 blocks/CU; co-resident blocks hide each other's barrier
// drains (R9 showed 2 blocks/CU regresses; this config is the local optimum).
// ---------------------------------------------------------------------------
static __device__ inline void load_chunk(const ushort* __restrict__ gsrc,
                                         ushort* ldst, int tid, int wave) {
    #pragma unroll
    for (int i = 0; i < 4; ++i) {
        const ushort* g = gsrc + (size_t)(i * 256 + tid) * 8;
        ushort* l = ldst + (size_t)(i * 256 + wave * 64) * 8;  // wave-uniform base
        __builtin_amdgcn_global_load_lds(
            (const __attribute__((address_space(1))) unsigned int*)g,
            (__attribute__((address_space(3))) unsigned int*)l, 16, 0, 0);
    }
}

template <bool CHECK>
__device__ __forceinline__ void kb_main(const float4* __restrict__ esl,
                                        const ushort* __restrict__ gsl,
                                        ushort (*sbuf)[8192],
                                        const float4 en, int k0m,
                                        int tid, int wave, int lane, int quad,
                                        floatx4 (&acc)[16], float& rowsum) {
    #pragma unroll 2
    for (int st = 0; st < CPS; ++st) {
        __syncthreads();   // chunk st resident; all reads of buf[st&1]'s prior life done
        if (st + 1 < CPS)
            load_chunk(gsl + (size_t)(st + 1) * 8192, sbuf[(st + 1) & 1], tid, wave);

        // scores for this step's A-fragment: lane holds A[rt*16+l15][quad*8+u]
        short8 af;
        const int stq = st * 32 + quad * 8;
        #pragma unroll
        for (int u = 0; u < 8; ++u) {
            float4 em = esl[stq + u];
            float dt = en.x*em.x + en.y*em.y + en.z*em.z + en.w*em.w;
            float sv = __expf(fmaxf(dt, 0.f));
            if (CHECK && (k0m + stq + u >= NN)) sv = 0.f;
            rowsum += sv;
            af[u] = (short)f2bf(sv);
        }

        const ushort* bb = &sbuf[st & 1][lane * 8];
        #pragma unroll
        for (int ct = 0; ct < 16; ++ct) {
            short8 bf = *(const short8*)&bb[ct * 512];
            acc[ct] = __builtin_amdgcn_mfma_f32_16x16x32_bf16(af, bf, acc[ct], 0, 0, 0);
        }
    }
}

__global__ __launch_bounds__(256, 4)
void kb_pg(const float* __restrict__ e, const ushort* __restrict__ gtf,
           float* __restrict__ pgp, float* __restrict__ rsums) {
    __shared__ ushort sbuf[2][8192];     // double-buffered B chunk, 32 KB
    __shared__ float4 esl[512];          // slice's E rows, 8 KB
    const int tid  = threadIdx.x;
    const int wave = tid >> 6;
    const int lane = tid & 63;
    const int l15  = lane & 15;
    const int quad = lane >> 4;
    const int rt   = blockIdx.x * 4 + wave;
    const int s    = blockIdx.y;
    const int k0m  = s * (CPS * 32);     // first m of slice
    const float4* E4 = (const float4*)e;

    // stage slice E rows + first B chunk
    for (int i = tid; i < 512; i += 256) {
        int m = k0m + i;
        esl[i] = (m < NN) ? E4[m] : make_float4(0.f, 0.f, 0.f, 0.f);
    }
    const ushort* gsl = gtf + (size_t)s * CPS * 8192;
    load_chunk(gsl, sbuf[0], tid, wave);

    const int nr = rt * 16 + l15;
    const float4 en = E4[nr < NN ? nr : 0];

    floatx4 acc[16];
    #pragma unroll
    for (int i = 0; i < 16; ++i) acc[i] = (floatx4){0.f, 0.f, 0.f, 0.f};
    float rowsum = 0.f;

    if (k0m + CPS * 32 <= NN)
        kb_main<false>(esl, gsl, sbuf, en, k0m, tid, wave, lane, quad, acc, rowsum);
    else
        kb_main<true >(esl, gsl, sbuf, en, k0m, tid, wave, lane, quad, acc, rowsum);

    // rsums: row l15, partial per quad -> butterfly over quads, quad0 stores
    rowsum += __shfl_xor(rowsum, 16);
    rowsum += __shfl_xor(rowsum, 32);
    if (quad == 0) rsums[(size_t)s * MPAD + nr] = rowsum;   // nr < MPAD always

    // epilogue: acc[ct][j] = D[n = rt*16+quad*4+j][dj = l15]
    // contract dj = d*4+jj with E[n,d]: reduce over d via shfl_xor(4),(8)
    const int dsel = l15 >> 2, jj = l15 & 3;
    float end[4];
    #pragma unroll
    for (int j = 0; j < 4; ++j) {
        int n = rt * 16 + quad * 4 + j;
        end[j] = (n < NN) ? e[n * 4 + dsel] : 0.f;
    }
    #pragma unroll
    for (int ct = 0; ct < 16; ++ct) {
        #pragma unroll
        for (int j = 0; j < 4; ++j) {
            float v = end[j] * acc[ct][j];
            v += __shfl_xor(v, 4);
            v += __shfl_xor(v, 8);
            int n = rt * 16 + quad * 4 + j;
            if (l15 < 4 && n < NN)
                pgp[(((size_t)s * BB + ct) * NN + n) * 4 + jj] = v;
        }
    }
}

// ---------------------------------------------------------------------------
// Kernel E: tiny epilogue
// pre[j] = g0c[b][n][j] + (1/sum_s rsums[s][n]) * sum_s pgp[s][b][n][j]
//          + sum_d E[n,d]*bias[d][j]
// R=sigmoid(pre[0..1]), C=tanh(pre[2..3]), h=(1-R)*C, y = relu(h)@lin_w + lin_b
// ---------------------------------------------------------------------------
static __device__ inline float fsig(float x) {
    return 1.f / (1.f + __expf(-x));
}
static __device__ inline float ftanh(float x) {
    float t = __expf(fminf(2.f * x, 80.f));
    return (t - 1.f) / (t + 1.f);
}

__global__ __launch_bounds__(256)
void ke_out(const float* __restrict__ e, const float* __restrict__ rsums,
            const float* __restrict__ g0c, const float* __restrict__ pgp,
            const float* __restrict__ bg, const float* __restrict__ bu,
            const float* __restrict__ lw, const float* __restrict__ lb,
            float* __restrict__ out) {
    int n = blockIdx.x * 256 + threadIdx.x;
    int b = blockIdx.y;
    if (n >= NN) return;
    float4 ev = ((const float4*)e)[n];
    float ed[4] = {ev.x, ev.y, ev.z, ev.w};
    float den = 0.f;
    #pragma unroll
    for (int s = 0; s < OUTER; ++s) den += rsums[(size_t)s * MPAD + n];
    float rd = 1.f / den;

    float pgf[4] = {0.f, 0.f, 0.f, 0.f};
    #pragma unroll
    for (int s = 0; s < OUTER; ++s) {
        float4 t = ((const float4*)pgp)[((size_t)s * BB + b) * NN + n];
        pgf[0] += t.x; pgf[1] += t.y; pgf[2] += t.z; pgf[3] += t.w;
    }
    float4 g0v = ((const float4*)g0c)[(size_t)b * NN + n];
    float g0f[4] = {g0v.x, g0v.y, g0v.z, g0v.w};

    float pre[4];
    #pragma unroll
    for (int j = 0; j < 4; ++j) {
        float bj = 0.f;
        #pragma unroll
        for (int d = 0; d < 4; ++d) {
            float bp = (j < 2) ? bg[d * 4 + 2 + j] : bu[d * 2 + (j - 2)];
            bj += ed[d] * bp;
        }
        pre[j] = g0f[j] + rd * pgf[j] + bj;
    }
    float R0 = fsig(pre[0]);
    float R1 = fsig(pre[1]);
    float C0 = ftanh(pre[2]);
    float C1 = ftanh(pre[3]);
    float h0 = (1.f - R0) * C0;
    float h1 = (1.f - R1) * C1;
    float y = fmaxf(h0, 0.f) * lw[0] + fmaxf(h1, 0.f) * lw[1] + lb[0];
    out[(size_t)b * NN + n] = y;
}

// ---------------------------------------------------------------------------
extern "C" void kernel_launch(void* const* d_in, const int* in_sizes, int n_in,
                              void* d_out, int out_size, void* d_ws, size_t ws_size,
                              hipStream_t stream) {
    const float* x  = (const float*)d_in[0];
    const float* e  = (const float*)d_in[1];
    const float* wg = (const float*)d_in[2];
    const float* bg = (const float*)d_in[3];
    const float* wu = (const float*)d_in[4];
    const float* bu = (const float*)d_in[5];
    const float* lw = (const float*)d_in[6];
    const float* lb = (const float*)d_in[7];
    float* out = (float*)d_out;

    float*  wsf   = (float*)d_ws;
    float*  rsums = wsf + OFF_RSUM;
    float*  g0c   = wsf + OFF_G0C;
    float*  pgp   = wsf + OFF_PGP;
    ushort* gtf   = (ushort*)(wsf + OFF_GTF);

    hipLaunchKernelGGL(kg_g, dim3(22, 16), dim3(256), 0, stream, x, e, wg, wu, g0c, gtf);
    hipLaunchKernelGGL(kb_pg, dim3(88, OUTER), dim3(256), 0, stream, e, gtf, pgp, rsums);
    hipLaunchKernelGGL(ke_out, dim3(22, 16), dim3(256), 0, stream,
                       e, rsums, g0c, pgp, bg, bu, lw, lb, out);
}